// Round 1
// baseline (2336.830 us; speedup 1.0000x reference)
//
#include <hip/hip_runtime.h>
#include <hip/hip_bf16.h>

// GenericLSTM: B=64 T=2048 I=128 H=256, fp32 in/out.
// Plan: (1) pack W_h -> int8 per-column-scaled, (2) pack W_x -> bf16 in MFMA
// fragment order, (3) one MFMA GEMM computes g_x = inputs@W_x for all t (f16),
// (4) persistent recurrent kernel: 1 WG per batch sample, W_h resident in
// VGPRs as int8, h carried as int8 in LDS, v_dot4 inner product, no cross-WG
// sync.

#define B_ 64
#define T_ 2048
#define I_ 128
#define H_ 256
#define NC 1024  // 4 gates * H columns

typedef __attribute__((ext_vector_type(8))) short bf16x8;
typedef __attribute__((ext_vector_type(4))) float f32x4;

static __device__ __forceinline__ unsigned short f2bf(float f) {
    unsigned u = __builtin_bit_cast(unsigned, f);
    u = (u + 0x7FFFu + ((u >> 16) & 1u)) >> 16;
    return (unsigned short)u;
}

static __device__ __forceinline__ int dot4(unsigned a, unsigned b, int c) {
#if __has_builtin(__builtin_amdgcn_sdot4)
    return __builtin_amdgcn_sdot4((int)a, (int)b, c, false);
#else
    int r = c;
    r += (int)(signed char)(a) * (int)(signed char)(b);
    r += (int)(signed char)(a >> 8) * (int)(signed char)(b >> 8);
    r += (int)(signed char)(a >> 16) * (int)(signed char)(b >> 16);
    r += (int)(signed char)(a >> 24) * (int)(signed char)(b >> 24);
    return r;
#endif
}

// ---------------- P1: W_h [4,256,256] f32 -> int8 packed [col][k/4 dwords] +
// per-col scale (scale already includes the 1/127 h dequant factor).
__global__ void pack_wh(const float* __restrict__ Wh, unsigned* __restrict__ wq,
                        float* __restrict__ sws) {
    int col = blockIdx.x;              // 0..1023 = g*256 + j
    int g = col >> 8, j = col & 255;
    int lane = threadIdx.x;            // 0..63, covers k = 4*lane..4*lane+3
    float v[4];
    float m = 0.f;
#pragma unroll
    for (int u = 0; u < 4; ++u) {
        int k = lane * 4 + u;
        v[u] = Wh[(g * H_ + k) * H_ + j];
        m = fmaxf(m, fabsf(v[u]));
    }
#pragma unroll
    for (int off = 32; off; off >>= 1) m = fmaxf(m, __shfl_xor(m, off));
    float mm = (m > 0.f) ? m : 1.f;
    float inv = 127.f / mm;
    unsigned pack = 0;
#pragma unroll
    for (int u = 0; u < 4; ++u) {
        int q = (int)rintf(v[u] * inv);
        q = max(-127, min(127, q));
        pack |= ((unsigned)(q & 255)) << (8 * u);
    }
    wq[col * 64 + lane] = pack;
    if (lane == 0) sws[col] = mm / (127.f * 127.f);  // S_col/127
}

// ---------------- P2: W_x [4,128,256] f32 -> bf16 in MFMA-fragment order:
// Bfrag[((ki*4+q)*1024 + col)*8 + j] = W_x[g][k][h], k = (ki)*32 + q*8 + j.
__global__ void pack_wx(const float* __restrict__ Wx,
                        unsigned short* __restrict__ bxp) {
    int f = blockIdx.x * blockDim.x + threadIdx.x;  // 0..131071
    int j = f & 7;
    int col = (f >> 3) & 1023;
    int c16 = f >> 13;  // 0..15
    int k = (c16 >> 2) * 32 + (c16 & 3) * 8 + j;
    int g = col >> 8, h = col & 255;
    bxp[f] = f2bf(Wx[(g * I_ + k) * H_ + h]);
}

// ---------------- GEMM: g_x[row][col] = sum_k inputs[row][k] * W_x[k][col]
// rows = b*T+t (131072), cols = 1024, K = 128 (single shot, no k-loop).
// Output stored as f16.
__global__ __launch_bounds__(256) void gemm_gx(
    const float* __restrict__ A, const unsigned short* __restrict__ Bp,
    unsigned short* __restrict__ Cg) {
    __shared__ uint4 sm[4096];  // 64 KB: As = [0..2047], Bs = [2048..4095]
    int tid = threadIdx.x;
    int mt = blockIdx.x, nt = blockIdx.y;

    // Stage A tile (128 rows x 128 k), f32 -> bf16, fragment-order layout:
    // As[(c16*128+m)] is a 16B vector holding k-j 0..7 for that (c16,m).
    const float* Ab = A + (size_t)mt * 128 * I_;
    unsigned* dstA = (unsigned*)sm;
#pragma unroll
    for (int it = 0; it < 16; ++it) {
        int flat = it * 1024 + tid * 4;
        float4 a4 = *(const float4*)(Ab + flat);
        int m = flat >> 7, k0 = flat & 127;
        int c16 = k0 >> 3, j0 = k0 & 7;  // j0 in {0,4}
        unsigned lo = (unsigned)f2bf(a4.x) | ((unsigned)f2bf(a4.y) << 16);
        unsigned hi = (unsigned)f2bf(a4.z) | ((unsigned)f2bf(a4.w) << 16);
        int didx = ((c16 * 128 + m) * 16 + j0 * 2) >> 2;
        dstA[didx] = lo;
        dstA[didx + 1] = hi;
    }
    // Stage B tile (prepacked fragment order): contiguous 16B per (c16,col).
    const uint4* Bq = (const uint4*)Bp;
#pragma unroll
    for (int it = 0; it < 8; ++it) {
        int chunk = it * 2 + (tid >> 7);
        int inner = tid & 127;
        sm[2048 + chunk * 128 + inner] = Bq[chunk * 1024 + nt * 128 + inner];
    }
    __syncthreads();

    int wid = tid >> 6, lane = tid & 63;
    int r = lane & 15, q = lane >> 4;
    int mw = (wid & 1) * 64, nw = (wid >> 1) * 64;
    f32x4 acc[4][4] = {};
#pragma unroll
    for (int ki = 0; ki < 4; ++ki) {
        bf16x8 af[4], bfr[4];
#pragma unroll
        for (int x = 0; x < 4; ++x) {
            af[x] = __builtin_bit_cast(bf16x8,
                                       sm[(ki * 4 + q) * 128 + mw + x * 16 + r]);
            bfr[x] = __builtin_bit_cast(
                bf16x8, sm[2048 + (ki * 4 + q) * 128 + nw + x * 16 + r]);
        }
#pragma unroll
        for (int x = 0; x < 4; ++x)
#pragma unroll
            for (int y = 0; y < 4; ++y)
                acc[x][y] = __builtin_amdgcn_mfma_f32_16x16x32_bf16(
                    af[x], bfr[y], acc[x][y], 0, 0, 0);
    }
    __syncthreads();

    // C frags (col=lane&15, row=q*4+reg) -> LDS f16 tile, then coalesced store.
    _Float16* ct = (_Float16*)sm;
#pragma unroll
    for (int x = 0; x < 4; ++x)
#pragma unroll
        for (int y = 0; y < 4; ++y)
#pragma unroll
            for (int g2 = 0; g2 < 4; ++g2) {
                int row = mw + x * 16 + q * 4 + g2;
                int colc = nw + y * 16 + r;
                ct[row * 128 + colc] = (_Float16)acc[x][y][g2];
            }
    __syncthreads();
    int m = tid >> 1, half = tid & 1;
    const uint4* src = (const uint4*)sm;
    uint4* dstg =
        (uint4*)(Cg + ((size_t)(mt * 128 + m) * NC + nt * 128 + half * 64));
#pragma unroll
    for (int i = 0; i < 8; ++i) dstg[i] = src[m * 16 + half * 8 + i];
}

// ---------------- Recurrent kernel: 64 WGs (1/sample) x 512 threads.
// Thread tid owns gate-cols {tid, tid+512}; W_h int8 resident in VGPRs.
// h carried as int8 (scale 1/127) in LDS, double buffered.
#define DOTQ(acc, hv, wv)            \
    acc = dot4(hv.x, wv.x, acc);     \
    acc = dot4(hv.y, wv.y, acc);     \
    acc = dot4(hv.z, wv.z, acc);     \
    acc = dot4(hv.w, wv.w, acc);

__global__ __launch_bounds__(512) void lstm_rec(
    const unsigned short* __restrict__ gx, const uint4* __restrict__ wq4,
    const float* __restrict__ sws, const float* __restrict__ bias,
    float* __restrict__ out) {
    int b = blockIdx.x, tid = threadIdx.x;
    int col0 = tid, col1 = tid + 512;

    uint4 w0[16], w1[16];
#pragma unroll
    for (int i = 0; i < 16; ++i) {
        w0[i] = wq4[col0 * 16 + i];
        w1[i] = wq4[col1 * 16 + i];
    }
    float s0 = sws[col0], s1 = sws[col1];
    float bb0 = bias[col0], bb1 = bias[col1];

    __shared__ uint4 hq[2][16];       // 256 int8 h values, double buffered
    __shared__ float p1buf[256];      // sigmoid(i)*tanh(g) exchange
    if (tid < 64) ((unsigned*)&hq[0][0])[tid] = 0u;
    __syncthreads();

    float c = 0.f;
    const _Float16* gxh = (const _Float16*)gx;
    size_t rowbase = (size_t)b * T_;
    float gx0 = (float)gxh[rowbase * NC + col0];
    float gx1 = (float)gxh[rowbase * NC + col1];

    for (int t = 0; t < T_; ++t) {
        size_t row = rowbase + t;
        // prefetch next step's g_x (t=2047 reads 2KB past gx: still inside ws)
        float nx0 = (float)gxh[(row + 1) * NC + col0];
        float nx1 = (float)gxh[(row + 1) * NC + col1];

        int a0 = 0, a1 = 0, a2 = 0, a3 = 0;
        const uint4* hb = hq[t & 1];
#pragma unroll
        for (int i = 0; i < 16; i += 2) {
            uint4 h0v = hb[i], h1v = hb[i + 1];
            DOTQ(a0, h0v, w0[i]);
            DOTQ(a2, h0v, w1[i]);
            DOTQ(a1, h1v, w0[i + 1]);
            DOTQ(a3, h1v, w1[i + 1]);
        }
        float g0 = (float)(a0 + a1) * s0 + gx0 + bb0;
        float g1 = (float)(a2 + a3) * s1 + gx1 + bb1;

        float r0 = 1.f / (1.f + __expf(-g0));  // sigmoid(i) or sigmoid(f)
        float r1;
        if (tid < 256) {  // wave-uniform branch (waves 0-3)
            float e = __expf(-2.f * g1);       // tanh(g_g)
            r1 = 2.f / (1.f + e) - 1.f;
            p1buf[tid] = r0 * r1;
        } else {
            r1 = 1.f / (1.f + __expf(-g1));    // sigmoid(o)
        }
        __syncthreads();
        if (tid >= 256) {  // waves 4-7 own the c/h state for H-col j
            int j = tid - 256;
            c = r0 * c + p1buf[j];
            float e = __expf(-2.f * c);
            float th = 2.f / (1.f + e) - 1.f;  // tanh(c), inf-safe
            float h = r1 * th;
            out[row * H_ + j] = h;
            int qv = (int)rintf(h * 127.f);
            ((signed char*)hq[(t + 1) & 1])[j] = (signed char)qv;
        }
        __syncthreads();
        gx0 = nx0;
        gx1 = nx1;
    }
}

extern "C" void kernel_launch(void* const* d_in, const int* in_sizes, int n_in,
                              void* d_out, int out_size, void* d_ws,
                              size_t ws_size, hipStream_t stream) {
    const float* inputs = (const float*)d_in[0];
    const float* Wx = (const float*)d_in[1];
    const float* Wh = (const float*)d_in[2];
    const float* bias = (const float*)d_in[3];
    float* out = (float*)d_out;

    char* ws = (char*)d_ws;
    unsigned short* gxbuf = (unsigned short*)ws;   // 131072*1024 f16 = 256 MiB
    size_t off = (size_t)B_ * T_ * NC * 2;
    unsigned* wq = (unsigned*)(ws + off);          // 256 KiB int8 W_h
    off += (size_t)NC * 64 * 4;
    float* sws = (float*)(ws + off);               // 4 KiB scales
    off += (size_t)NC * 4;
    unsigned short* bxp = (unsigned short*)(ws + off);  // 256 KiB bf16 W_x
    off += (size_t)I_ * NC * 2;

    pack_wh<<<NC, 64, 0, stream>>>(Wh, wq, sws);
    pack_wx<<<(I_ * NC) / 256, 256, 0, stream>>>(Wx, bxp);
    gemm_gx<<<dim3((B_ * T_) / 128, NC / 128), 256, 0, stream>>>(inputs, bxp,
                                                                 gxbuf);
    lstm_rec<<<B_, 512, 0, stream>>>(gxbuf, (const uint4*)wq, sws, bias, out);
}